// Round 1
// baseline (7131.067 us; speedup 1.0000x reference)
//
#include <hip/hip_runtime.h>
#include <hip/hip_bf16.h>
#include <math.h>

#define L_SEQ 512
#define N_B   64
#define H_D   512
#define M_TOT (L_SEQ * N_B)   // 32768

typedef unsigned short u16;
typedef __attribute__((ext_vector_type(8))) short short8;
typedef __attribute__((ext_vector_type(4))) float f32x4;

__device__ __forceinline__ u16 f2bf(float f) {
    unsigned int u = __builtin_bit_cast(unsigned int, f);
    u = u + 0x7fffu + ((u >> 16) & 1u);
    return (u16)(u >> 16);
}

// ---- prep: fp32->bf16 conversions, bias sums, flag zeroing ----
__global__ void k_prep(const float* __restrict__ x,
                       const float* __restrict__ w0ih, const float* __restrict__ w0hh,
                       const float* __restrict__ b0i,  const float* __restrict__ b0h,
                       const float* __restrict__ w1ih, const float* __restrict__ w1hh,
                       const float* __restrict__ b1i,  const float* __restrict__ b1h,
                       u16* __restrict__ xb,
                       u16* __restrict__ w0ihb, u16* __restrict__ w0hhb,
                       u16* __restrict__ w1ihb, u16* __restrict__ w1hhb,
                       float* __restrict__ bias0, float* __restrict__ bias1,
                       int* __restrict__ flags0, int* __restrict__ flags1)
{
    const int stride = gridDim.x * blockDim.x;
    const int tid = blockIdx.x * blockDim.x + threadIdx.x;
    for (int i = tid; i < M_TOT * H_D / 4; i += stride) {
        const float4 v = ((const float4*)x)[i];
        ushort4 o;
        o.x = f2bf(v.x); o.y = f2bf(v.y); o.z = f2bf(v.z); o.w = f2bf(v.w);
        ((ushort4*)xb)[i] = o;
    }
    for (int i = tid; i < H_D * H_D; i += stride) {
        w0ihb[i] = f2bf(w0ih[i]);
        w0hhb[i] = f2bf(w0hh[i]);
        w1ihb[i] = f2bf(w1ih[i]);
        w1hhb[i] = f2bf(w1hh[i]);
    }
    if (tid < H_D) {
        bias0[tid] = b0i[tid] + b0h[tid];
        bias1[tid] = b1i[tid] + b1h[tid];
    }
    if (tid < L_SEQ) { flags0[tid] = 0; flags1[tid] = 0; }
}

// ---- big parallel GEMM: out[M,512] = A[M,512](bf16) @ W[512,512]^T(bf16) + bias ----
// 128x128 tile per block, 256 threads (4 waves), 16x16x32 bf16 MFMA.
__global__ __launch_bounds__(256)
void k_gemm(const u16* __restrict__ A, const u16* __restrict__ W,
            const float* __restrict__ bias, float* __restrict__ out)
{
    __shared__ u16 As[128][40];   // +8 pad breaks bank conflicts
    __shared__ u16 Ws[128][40];
    const int m0 = blockIdx.x * 128;
    const int n0 = blockIdx.y * 128;
    const int tid = threadIdx.x;
    const int w = tid >> 6, l = tid & 63, q = l >> 4, lr = l & 15;
    const int mw = (w >> 1) * 64, nw = (w & 1) * 64;
    const int skg = (tid & 3) * 8;      // staging k offset (8 bf16 = 16B)
    const int smr = tid >> 2;           // staging row 0..63

    f32x4 acc[4][4];
    #pragma unroll
    for (int i = 0; i < 4; ++i)
        #pragma unroll
        for (int j = 0; j < 4; ++j)
            acc[i][j] = (f32x4){0.f, 0.f, 0.f, 0.f};

    for (int kk = 0; kk < H_D; kk += 32) {
        *(uint4*)&As[smr][skg]      = *(const uint4*)(A + (size_t)(m0 + smr) * H_D + kk + skg);
        *(uint4*)&As[smr + 64][skg] = *(const uint4*)(A + (size_t)(m0 + smr + 64) * H_D + kk + skg);
        *(uint4*)&Ws[smr][skg]      = *(const uint4*)(W + (size_t)(n0 + smr) * H_D + kk + skg);
        *(uint4*)&Ws[smr + 64][skg] = *(const uint4*)(W + (size_t)(n0 + smr + 64) * H_D + kk + skg);
        __syncthreads();
        short8 af[4], bf[4];
        #pragma unroll
        for (int rt = 0; rt < 4; ++rt) af[rt] = *(const short8*)&As[mw + rt*16 + lr][q*8];
        #pragma unroll
        for (int nt = 0; nt < 4; ++nt) bf[nt] = *(const short8*)&Ws[nw + nt*16 + lr][q*8];
        #pragma unroll
        for (int rt = 0; rt < 4; ++rt)
            #pragma unroll
            for (int nt = 0; nt < 4; ++nt)
                acc[rt][nt] = __builtin_amdgcn_mfma_f32_16x16x32_bf16(af[rt], bf[nt], acc[rt][nt], 0, 0, 0);
        __syncthreads();
    }
    #pragma unroll
    for (int nt = 0; nt < 4; ++nt) {
        const int col = n0 + nw + nt*16 + lr;
        const float bv = bias[col];
        #pragma unroll
        for (int rt = 0; rt < 4; ++rt) {
            #pragma unroll
            for (int r = 0; r < 4; ++r) {
                const int row = m0 + mw + rt*16 + q*4 + r;
                out[(size_t)row * H_D + col] = acc[rt][nt][r] + bv;
            }
        }
    }
}

// ---- recurrence: h[t] = tanh(pre[t] + h[t-1] @ Whh^T) ----
// 16 WGs, each owns 32 output columns; Whh slice lives in VGPRs (128/lane).
// Cross-WG sync: one atomic counter per timestep.
template<int PHASE>
__global__ __launch_bounds__(256)
void k_rec(const u16* __restrict__ Whh,
           const float* __restrict__ h_init,
           const float* __restrict__ pre,
           u16* __restrict__ hist_bf,
           float* __restrict__ hist_f32,
           float* __restrict__ hn_out,
           int* __restrict__ flags)
{
    const int tid = threadIdx.x;
    const int c = blockIdx.x;             // 0..15 column slice
    const int w = tid >> 6, l = tid & 63, q = l >> 4, lr = l & 15;
    const int r0 = w * 16;                // wave's 16 batch rows
    const int nbase = c * 32;

    // preload B fragments (W_hh slice) into registers: 16 k-tiles x 2 n-tiles
    short8 breg[16][2];
    #pragma unroll
    for (int kt = 0; kt < 16; ++kt) {
        #pragma unroll
        for (int nt = 0; nt < 2; ++nt) {
            const int n = nbase + nt*16 + lr;
            const int k = kt*32 + q*8;
            breg[kt][nt] = *(const short8*)(Whh + (size_t)n * H_D + k);
        }
    }

    for (int t = 0; t < L_SEQ; ++t) {
        // init accumulators from precomputed input transform (independent of peers)
        const float* pt = pre + (size_t)t * N_B * H_D;
        f32x4 acc[2];
        #pragma unroll
        for (int nt = 0; nt < 2; ++nt) {
            const int col = nbase + nt*16 + lr;
            #pragma unroll
            for (int r = 0; r < 4; ++r)
                acc[nt][r] = pt[(size_t)(r0 + q*4 + r) * H_D + col];
        }
        // wait until all 16 WGs have published step t-1
        if (t > 0) {
            if (tid == 0)
                while (__hip_atomic_load(flags + t - 1, __ATOMIC_RELAXED, __HIP_MEMORY_SCOPE_AGENT) != 16) { }
            __syncthreads();
            __threadfence();   // acquire: invalidate caches so peers' h is visible
        }
        const int m = r0 + lr;
        if (t == 0) {
            #pragma unroll
            for (int kt = 0; kt < 16; ++kt) {
                const int k = kt*32 + q*8;
                const float* s = h_init + (size_t)m * H_D + k;
                short8 a;
                #pragma unroll
                for (int j = 0; j < 8; ++j) a[j] = (short)f2bf(s[j]);
                acc[0] = __builtin_amdgcn_mfma_f32_16x16x32_bf16(a, breg[kt][0], acc[0], 0, 0, 0);
                acc[1] = __builtin_amdgcn_mfma_f32_16x16x32_bf16(a, breg[kt][1], acc[1], 0, 0, 0);
            }
        } else {
            const u16* hsrc = hist_bf + ((size_t)(t - 1) * N_B + m) * H_D;
            #pragma unroll
            for (int kt = 0; kt < 16; ++kt) {
                short8 a = *(const short8*)(hsrc + kt*32 + q*8);
                acc[0] = __builtin_amdgcn_mfma_f32_16x16x32_bf16(a, breg[kt][0], acc[0], 0, 0, 0);
                acc[1] = __builtin_amdgcn_mfma_f32_16x16x32_bf16(a, breg[kt][1], acc[1], 0, 0, 0);
            }
        }
        // tanh + store h[t]
        #pragma unroll
        for (int nt = 0; nt < 2; ++nt) {
            const int col = nbase + nt*16 + lr;
            #pragma unroll
            for (int r = 0; r < 4; ++r) {
                const int row = r0 + q*4 + r;
                const float h = tanhf(acc[nt][r]);
                hist_bf[((size_t)t * N_B + row) * H_D + col] = f2bf(h);
                if (PHASE == 1)
                    hist_f32[((size_t)t * N_B + row) * H_D + col] = h;
                if (t == L_SEQ - 1)
                    hn_out[(size_t)row * H_D + col] = h;
            }
        }
        // publish step t
        __threadfence();
        __syncthreads();
        if (tid == 0)
            __hip_atomic_fetch_add(flags + t, 1, __ATOMIC_RELAXED, __HIP_MEMORY_SCOPE_AGENT);
    }
}

extern "C" void kernel_launch(void* const* d_in, const int* in_sizes, int n_in,
                              void* d_out, int out_size, void* d_ws, size_t ws_size,
                              hipStream_t stream)
{
    (void)in_sizes; (void)n_in; (void)out_size; (void)ws_size;
    const float* x    = (const float*)d_in[0];
    const float* h0   = (const float*)d_in[1];
    const float* w0ih = (const float*)d_in[2];
    const float* w0hh = (const float*)d_in[3];
    const float* b0i  = (const float*)d_in[4];
    const float* b0h  = (const float*)d_in[5];
    const float* w1ih = (const float*)d_in[6];
    const float* w1hh = (const float*)d_in[7];
    const float* b1i  = (const float*)d_in[8];
    const float* b1h  = (const float*)d_in[9];
    float* out = (float*)d_out;

    char* ws = (char*)d_ws;
    size_t off = 0;
    u16* xb    = (u16*)(ws + off);     off += (size_t)M_TOT * H_D * 2;   // 32 MB
    u16* w0ihb = (u16*)(ws + off);     off += (size_t)H_D * H_D * 2;
    u16* w0hhb = (u16*)(ws + off);     off += (size_t)H_D * H_D * 2;
    u16* w1ihb = (u16*)(ws + off);     off += (size_t)H_D * H_D * 2;
    u16* w1hhb = (u16*)(ws + off);     off += (size_t)H_D * H_D * 2;
    float* bias0 = (float*)(ws + off); off += H_D * 4;
    float* bias1 = (float*)(ws + off); off += H_D * 4;
    int* flags0  = (int*)(ws + off);   off += L_SEQ * 4;
    int* flags1  = (int*)(ws + off);   off += L_SEQ * 4;
    float* pre0  = (float*)(ws + off); off += (size_t)M_TOT * H_D * 4;   // 64 MB
    u16* hbuf    = (u16*)(ws + off);   off += (size_t)M_TOT * H_D * 2;   // 32 MB, reused by phase 1

    // 1) convert inputs/weights to bf16, sum biases, zero flags
    k_prep<<<2048, 256, 0, stream>>>(x, w0ih, w0hh, b0i, b0h, w1ih, w1hh, b1i, b1h,
                                     xb, w0ihb, w0hhb, w1ihb, w1hhb,
                                     bias0, bias1, flags0, flags1);
    // 2) pre0 = x @ W_ih0^T + (b_ih0 + b_hh0)
    k_gemm<<<dim3(M_TOT/128, H_D/128), 256, 0, stream>>>(xb, w0ihb, bias0, pre0);
    // 3) layer-0 recurrence -> hbuf (bf16 history), h_n[0]
    k_rec<0><<<16, 256, 0, stream>>>(w0hhb, h0, pre0, hbuf, nullptr,
                                     out + (size_t)M_TOT * H_D, flags0);
    // 4) pre1 = h0_all @ W_ih1^T + (b_ih1 + b_hh1), written into d_out (scratch)
    k_gemm<<<dim3(M_TOT/128, H_D/128), 256, 0, stream>>>(hbuf, w1ihb, bias1, out);
    // 5) layer-1 recurrence, in-place over pre1 in d_out; also h_n[1]
    k_rec<1><<<16, 256, 0, stream>>>(w1hhb, h0 + N_B * H_D, out, hbuf, out,
                                     out + (size_t)M_TOT * H_D + N_B * H_D, flags1);
}

// Round 2
// 4369.331 us; speedup vs baseline: 1.6321x; 1.6321x over previous
//
#include <hip/hip_runtime.h>
#include <hip/hip_bf16.h>
#include <math.h>

#define L_SEQ 512
#define N_B   64
#define H_D   512
#define M_TOT (L_SEQ * N_B)   // 32768

typedef unsigned short u16;
typedef unsigned long long u64;
typedef __attribute__((ext_vector_type(8))) short short8;
typedef __attribute__((ext_vector_type(4))) float f32x4;

__device__ __forceinline__ u16 f2bf(float f) {
    unsigned int u = __builtin_bit_cast(unsigned int, f);
    u = u + 0x7fffu + ((u >> 16) & 1u);
    return (u16)(u >> 16);
}

__device__ __forceinline__ float fast_tanh(float x) {
    // safe at +-inf: e->inf gives 1-0, e->0 gives -1
    float e = __expf(2.0f * x);
    return 1.0f - 2.0f / (e + 1.0f);
}

// coherent (LLC, sc1) primitives — no cache-maintenance fences anywhere
__device__ __forceinline__ short8 ld_frag(const u16* p) {
    union { short8 v; u64 d[2]; } u;
    u.d[0] = __hip_atomic_load((const u64*)p,       __ATOMIC_RELAXED, __HIP_MEMORY_SCOPE_AGENT);
    u.d[1] = __hip_atomic_load((const u64*)(p + 4), __ATOMIC_RELAXED, __HIP_MEMORY_SCOPE_AGENT);
    return u.v;
}
__device__ __forceinline__ void st_h(u16* p, u16 v) {
    __hip_atomic_store(p, v, __ATOMIC_RELAXED, __HIP_MEMORY_SCOPE_AGENT);
}
__device__ __forceinline__ void st_flag(int* p, int v) {
    __hip_atomic_store(p, v, __ATOMIC_RELAXED, __HIP_MEMORY_SCOPE_AGENT);
}
// wait until all nprod producer flag words (layout [c][4w]) reach >= need
template<int NPROD>
__device__ __forceinline__ void wait_flags(const int* fl, int w, int need) {
    const int l = threadIdx.x & 63;
    const int* p = fl + (l & (NPROD - 1)) * 4 + w;
    while (true) {
        int v = __hip_atomic_load(p, __ATOMIC_RELAXED, __HIP_MEMORY_SCOPE_AGENT);
        if (__all(v >= need)) break;
    }
    asm volatile("" ::: "memory");
}

// ---- prep: fp32->bf16 conversions, bias sums, flag zeroing ----
__global__ void k_prep(const float* __restrict__ x,
                       const float* __restrict__ w0ih, const float* __restrict__ w0hh,
                       const float* __restrict__ b0i,  const float* __restrict__ b0h,
                       const float* __restrict__ w1ih, const float* __restrict__ w1hh,
                       const float* __restrict__ b1i,  const float* __restrict__ b1h,
                       u16* __restrict__ xb,
                       u16* __restrict__ w0ihb, u16* __restrict__ w0hhb,
                       u16* __restrict__ w1ihb, u16* __restrict__ w1hhb,
                       float* __restrict__ bias0, float* __restrict__ bias1,
                       int* __restrict__ flags)
{
    const int stride = gridDim.x * blockDim.x;
    const int tid = blockIdx.x * blockDim.x + threadIdx.x;
    for (int i = tid; i < M_TOT * H_D / 4; i += stride) {
        const float4 v = ((const float4*)x)[i];
        ushort4 o;
        o.x = f2bf(v.x); o.y = f2bf(v.y); o.z = f2bf(v.z); o.w = f2bf(v.w);
        ((ushort4*)xb)[i] = o;
    }
    for (int i = tid; i < H_D * H_D; i += stride) {
        w0ihb[i] = f2bf(w0ih[i]);
        w0hhb[i] = f2bf(w0hh[i]);
        w1ihb[i] = f2bf(w1ih[i]);
        w1hhb[i] = f2bf(w1hh[i]);
    }
    if (tid < H_D) {
        bias0[tid] = b0i[tid] + b0h[tid];
        bias1[tid] = b1i[tid] + b1h[tid];
    }
    if (tid < 192) flags[tid] = 0;   // flags0: 64 ints, flags1: 128 ints
}

// ---- big parallel GEMM: out[M,512] = A @ W^T + bias (bf16 MFMA) ----
__global__ __launch_bounds__(256)
void k_gemm(const u16* __restrict__ A, const u16* __restrict__ W,
            const float* __restrict__ bias, float* __restrict__ out)
{
    __shared__ u16 As[128][40];
    __shared__ u16 Ws[128][40];
    const int m0 = blockIdx.x * 128;
    const int n0 = blockIdx.y * 128;
    const int tid = threadIdx.x;
    const int w = tid >> 6, l = tid & 63, q = l >> 4, lr = l & 15;
    const int mw = (w >> 1) * 64, nw = (w & 1) * 64;
    const int skg = (tid & 3) * 8;
    const int smr = tid >> 2;

    f32x4 acc[4][4];
    #pragma unroll
    for (int i = 0; i < 4; ++i)
        #pragma unroll
        for (int j = 0; j < 4; ++j)
            acc[i][j] = (f32x4){0.f, 0.f, 0.f, 0.f};

    for (int kk = 0; kk < H_D; kk += 32) {
        *(uint4*)&As[smr][skg]      = *(const uint4*)(A + (size_t)(m0 + smr) * H_D + kk + skg);
        *(uint4*)&As[smr + 64][skg] = *(const uint4*)(A + (size_t)(m0 + smr + 64) * H_D + kk + skg);
        *(uint4*)&Ws[smr][skg]      = *(const uint4*)(W + (size_t)(n0 + smr) * H_D + kk + skg);
        *(uint4*)&Ws[smr + 64][skg] = *(const uint4*)(W + (size_t)(n0 + smr + 64) * H_D + kk + skg);
        __syncthreads();
        short8 af[4], bf[4];
        #pragma unroll
        for (int rt = 0; rt < 4; ++rt) af[rt] = *(const short8*)&As[mw + rt*16 + lr][q*8];
        #pragma unroll
        for (int nt = 0; nt < 4; ++nt) bf[nt] = *(const short8*)&Ws[nw + nt*16 + lr][q*8];
        #pragma unroll
        for (int rt = 0; rt < 4; ++rt)
            #pragma unroll
            for (int nt = 0; nt < 4; ++nt)
                acc[rt][nt] = __builtin_amdgcn_mfma_f32_16x16x32_bf16(af[rt], bf[nt], acc[rt][nt], 0, 0, 0);
        __syncthreads();
    }
    #pragma unroll
    for (int nt = 0; nt < 4; ++nt) {
        const int col = n0 + nw + nt*16 + lr;
        const float bv = bias[col];
        #pragma unroll
        for (int rt = 0; rt < 4; ++rt) {
            #pragma unroll
            for (int r = 0; r < 4; ++r) {
                const int row = m0 + mw + rt*16 + q*4 + r;
                out[(size_t)row * H_D + col] = acc[rt][nt][r] + bv;
            }
        }
    }
}

// ---- fused 2-layer recurrence, pipelined across layers ----
// blocks 0..15: layer 0, 32-col slices.  blocks 16..47: layer 1, 16-col slices.
// hbuf slot s holds h[t = s-1]; slot 0 = h_init (written in-kernel, stage 0).
// flags layout [c][4w], value = number of slots published by producer wave (c,w).
__global__ __launch_bounds__(256, 1)
void k_rec_fused(const u16* __restrict__ Whh0, const u16* __restrict__ Wih1,
                 const u16* __restrict__ Whh1,
                 const float* __restrict__ h_init,
                 const float* __restrict__ pre0,
                 const float* __restrict__ bias1,
                 u16* __restrict__ h0buf, u16* __restrict__ h1buf,
                 float* __restrict__ out, float* __restrict__ hn,
                 int* __restrict__ flags0, int* __restrict__ flags1)
{
    const int tid = threadIdx.x;
    const int w = tid >> 6, l = tid & 63, q = l >> 4, lr = l & 15;
    const int r0 = w * 16;          // this wave's 16 batch rows
    const int m = r0 + lr;          // A-fragment row for this lane

    if (blockIdx.x < 16) {
        // ================= layer 0: 32 columns =================
        const int c = blockIdx.x;
        const int nbase = c * 32;
        short8 breg[16][2];
        #pragma unroll
        for (int kt = 0; kt < 16; ++kt)
            #pragma unroll
            for (int nt = 0; nt < 2; ++nt)
                breg[kt][nt] = *(const short8*)(Whh0 + (size_t)(nbase + nt*16 + lr) * H_D + kt*32 + q*8);

        // stage 0: publish h_init (slot 0) for our 16 rows x 32 cols
        #pragma unroll
        for (int j = 0; j < 8; ++j) {
            int idx = l * 8 + j;                       // 0..511 over 16x32 block
            int row = r0 + (idx >> 5);
            int col = nbase + (idx & 31);
            st_h(h0buf + (size_t)row * H_D + col, f2bf(h_init[row * H_D + col]));
        }
        asm volatile("s_waitcnt vmcnt(0)" ::: "memory");
        if (l == 0) st_flag(flags0 + c*4 + w, 1);

        for (int t = 0; t < L_SEQ; ++t) {
            f32x4 acc0, acc1;
            const float* pt = pre0 + (size_t)t * (N_B * H_D);
            #pragma unroll
            for (int r = 0; r < 4; ++r) {
                acc0[r] = pt[(size_t)(r0 + q*4 + r) * H_D + nbase + lr];
                acc1[r] = pt[(size_t)(r0 + q*4 + r) * H_D + nbase + 16 + lr];
            }
            wait_flags<16>(flags0, w, t + 1);          // h[t-1] = slot t ready
            const u16* hs = h0buf + ((size_t)t * N_B + m) * H_D;
            short8 af[16];
            #pragma unroll
            for (int kt = 0; kt < 16; ++kt) af[kt] = ld_frag(hs + kt*32 + q*8);
            #pragma unroll
            for (int kt = 0; kt < 16; ++kt) {
                acc0 = __builtin_amdgcn_mfma_f32_16x16x32_bf16(af[kt], breg[kt][0], acc0, 0, 0, 0);
                acc1 = __builtin_amdgcn_mfma_f32_16x16x32_bf16(af[kt], breg[kt][1], acc1, 0, 0, 0);
            }
            u16* hd = h0buf + (size_t)(t + 1) * (N_B * H_D);
            #pragma unroll
            for (int r = 0; r < 4; ++r) {
                int row = r0 + q*4 + r;
                float v0 = fast_tanh(acc0[r]);
                float v1 = fast_tanh(acc1[r]);
                st_h(hd + (size_t)row * H_D + nbase + lr,      f2bf(v0));
                st_h(hd + (size_t)row * H_D + nbase + 16 + lr, f2bf(v1));
                if (t == L_SEQ - 1) {
                    hn[(size_t)row * H_D + nbase + lr]      = v0;
                    hn[(size_t)row * H_D + nbase + 16 + lr] = v1;
                }
            }
            asm volatile("s_waitcnt vmcnt(0)" ::: "memory");
            if (l == 0) st_flag(flags0 + c*4 + w, t + 2);
        }
    } else {
        // ================= layer 1: 16 columns =================
        const int c = blockIdx.x - 16;                 // 0..31
        const int nbase = c * 16;
        short8 bregI[16], bregH[16];
        #pragma unroll
        for (int kt = 0; kt < 16; ++kt) {
            bregI[kt] = *(const short8*)(Wih1 + (size_t)(nbase + lr) * H_D + kt*32 + q*8);
            bregH[kt] = *(const short8*)(Whh1 + (size_t)(nbase + lr) * H_D + kt*32 + q*8);
        }
        const float bv = bias1[nbase + lr];

        // stage 0: publish layer-1 h_init (slot 0), 16 rows x 16 cols
        const float* hi1 = h_init + N_B * H_D;
        #pragma unroll
        for (int j = 0; j < 4; ++j) {
            int idx = l * 4 + j;                       // 0..255 over 16x16 block
            int row = r0 + (idx >> 4);
            int col = nbase + (idx & 15);
            st_h(h1buf + (size_t)row * H_D + col, f2bf(hi1[row * H_D + col]));
        }
        asm volatile("s_waitcnt vmcnt(0)" ::: "memory");
        if (l == 0) st_flag(flags1 + c*4 + w, 1);

        for (int t = 0; t < L_SEQ; ++t) {
            f32x4 acc = {bv, bv, bv, bv};
            wait_flags<16>(flags0, w, t + 2);          // h0[t] = slot t+1 ready
            const u16* hs0 = h0buf + ((size_t)(t + 1) * N_B + m) * H_D;
            short8 a0[16];
            #pragma unroll
            for (int kt = 0; kt < 16; ++kt) a0[kt] = ld_frag(hs0 + kt*32 + q*8);
            #pragma unroll
            for (int kt = 0; kt < 16; ++kt)
                acc = __builtin_amdgcn_mfma_f32_16x16x32_bf16(a0[kt], bregI[kt], acc, 0, 0, 0);
            wait_flags<32>(flags1, w, t + 1);          // h1[t-1] = slot t ready
            const u16* hs1 = h1buf + ((size_t)t * N_B + m) * H_D;
            #pragma unroll
            for (int kt = 0; kt < 16; ++kt) {
                short8 a1 = ld_frag(hs1 + kt*32 + q*8);
                acc = __builtin_amdgcn_mfma_f32_16x16x32_bf16(a1, bregH[kt], acc, 0, 0, 0);
            }
            u16* hd = h1buf + (size_t)(t + 1) * (N_B * H_D);
            float* od = out + (size_t)t * (N_B * H_D);
            #pragma unroll
            for (int r = 0; r < 4; ++r) {
                int row = r0 + q*4 + r;
                float v = fast_tanh(acc[r]);
                st_h(hd + (size_t)row * H_D + nbase + lr, f2bf(v));
                od[(size_t)row * H_D + nbase + lr] = v;
                if (t == L_SEQ - 1)
                    hn[(size_t)(N_B + row) * H_D + nbase + lr] = v;
            }
            asm volatile("s_waitcnt vmcnt(0)" ::: "memory");
            if (l == 0) st_flag(flags1 + c*4 + w, t + 2);
        }
    }
}

extern "C" void kernel_launch(void* const* d_in, const int* in_sizes, int n_in,
                              void* d_out, int out_size, void* d_ws, size_t ws_size,
                              hipStream_t stream)
{
    (void)in_sizes; (void)n_in; (void)out_size; (void)ws_size;
    const float* x    = (const float*)d_in[0];
    const float* h0   = (const float*)d_in[1];
    const float* w0ih = (const float*)d_in[2];
    const float* w0hh = (const float*)d_in[3];
    const float* b0i  = (const float*)d_in[4];
    const float* b0h  = (const float*)d_in[5];
    const float* w1ih = (const float*)d_in[6];
    const float* w1hh = (const float*)d_in[7];
    const float* b1i  = (const float*)d_in[8];
    const float* b1h  = (const float*)d_in[9];
    float* out = (float*)d_out;
    float* hn  = out + (size_t)M_TOT * H_D;

    char* ws = (char*)d_ws;
    size_t off = 0;
    u16* w0ihb = (u16*)(ws + off);   off += (size_t)H_D * H_D * 2;
    u16* w0hhb = (u16*)(ws + off);   off += (size_t)H_D * H_D * 2;
    u16* w1ihb = (u16*)(ws + off);   off += (size_t)H_D * H_D * 2;
    u16* w1hhb = (u16*)(ws + off);   off += (size_t)H_D * H_D * 2;
    float* bias0 = (float*)(ws + off); off += H_D * 4;
    float* bias1 = (float*)(ws + off); off += H_D * 4;
    int* flags   = (int*)(ws + off);   off += 256 * 4;      // flags0 (64) + flags1 (128)
    int* flags0  = flags;
    int* flags1  = flags + 64;
    u16* h0buf   = (u16*)(ws + off);   off += (size_t)(L_SEQ + 1) * N_B * H_D * 2;  // 33.6 MB
    float* pre0  = (float*)(ws + off); off += (size_t)M_TOT * H_D * 4;              // 64 MB
    // xb (32 MB, only live until GEMM completes) aliases h1buf (33.6 MB)
    u16* h1buf   = (u16*)(ws + off);   off += (size_t)(L_SEQ + 1) * N_B * H_D * 2;
    u16* xb      = h1buf;

    // 1) convert inputs/weights to bf16, sum biases, zero flags
    k_prep<<<2048, 256, 0, stream>>>(x, w0ih, w0hh, b0i, b0h, w1ih, w1hh, b1i, b1h,
                                     xb, w0ihb, w0hhb, w1ihb, w1hhb,
                                     bias0, bias1, flags);
    // 2) pre0 = x @ W_ih0^T + (b_ih0 + b_hh0)
    k_gemm<<<dim3(M_TOT/128, H_D/128), 256, 0, stream>>>(xb, w0ihb, bias0, pre0);
    // 3) fused pipelined 2-layer recurrence
    k_rec_fused<<<48, 256, 0, stream>>>(w0hhb, w1ihb, w1hhb, h0, pre0, bias1,
                                        h0buf, h1buf, out, hn, flags0, flags1);
}

// Round 3
// 3819.902 us; speedup vs baseline: 1.8668x; 1.1438x over previous
//
#include <hip/hip_runtime.h>
#include <hip/hip_bf16.h>
#include <math.h>

#define L_SEQ 512
#define N_B   64
#define H_D   512
#define M_TOT (L_SEQ * N_B)   // 32768

typedef unsigned short u16;
typedef unsigned long long u64;
typedef __attribute__((ext_vector_type(8))) short short8;
typedef __attribute__((ext_vector_type(4))) float f32x4;
typedef __attribute__((ext_vector_type(4))) int i32x4;

__device__ __forceinline__ u16 f2bf(float f) {
    unsigned int u = __builtin_bit_cast(unsigned int, f);
    u = u + 0x7fffu + ((u >> 16) & 1u);
    return (u16)(u >> 16);
}

__device__ __forceinline__ float fast_tanh(float x) {
    float e = __expf(2.0f * x);
    return 1.0f - 2.0f / (e + 1.0f);
}

__device__ __forceinline__ void st_h(u16* p, u16 v) {
    __hip_atomic_store(p, v, __ATOMIC_RELAXED, __HIP_MEMORY_SCOPE_AGENT);
}
__device__ __forceinline__ void st_flag(int* p, int v) {
    __hip_atomic_store(p, v, __ATOMIC_RELAXED, __HIP_MEMORY_SCOPE_AGENT);
}
// all 16 producer words (layout [c][4w]) must reach >= need
__device__ __forceinline__ void wait_flags16(const int* fl, int w, int need) {
    const int l = threadIdx.x & 63;
    const int* p = fl + (l & 15) * 4 + w;
    while (true) {
        int v = __hip_atomic_load(p, __ATOMIC_RELAXED, __HIP_MEMORY_SCOPE_AGENT);
        if (__all(v >= need)) break;
    }
    asm volatile("" ::: "memory");
}
// combined wait: flags0 (16 words) >= t+2 AND flags1 (32 words) >= t+1
__device__ __forceinline__ void wait_flags_l1(const int* f0, const int* f1, int w, int t) {
    const int l = threadIdx.x & 63;
    const int* p;
    int need;
    if (l < 16)      { p = f0 + l * 4 + w;        need = t + 2; }
    else if (l < 48) { p = f1 + (l - 16) * 4 + w; need = t + 1; }
    else             { p = f0 + w;                need = 0;     }
    while (true) {
        int v = __hip_atomic_load(p, __ATOMIC_RELAXED, __HIP_MEMORY_SCOPE_AGENT);
        if (__all(v >= need)) break;
    }
    asm volatile("" ::: "memory");
}

// 16 device-coherent 16B loads (512B of one row) + single drain
#define LD16(f, p)                                                          \
  asm volatile(                                                             \
    "global_load_dwordx4 %0, %16, off sc1\n\t"                              \
    "global_load_dwordx4 %1, %16, off offset:64 sc1\n\t"                    \
    "global_load_dwordx4 %2, %16, off offset:128 sc1\n\t"                   \
    "global_load_dwordx4 %3, %16, off offset:192 sc1\n\t"                   \
    "global_load_dwordx4 %4, %16, off offset:256 sc1\n\t"                   \
    "global_load_dwordx4 %5, %16, off offset:320 sc1\n\t"                   \
    "global_load_dwordx4 %6, %16, off offset:384 sc1\n\t"                   \
    "global_load_dwordx4 %7, %16, off offset:448 sc1\n\t"                   \
    "global_load_dwordx4 %8, %16, off offset:512 sc1\n\t"                   \
    "global_load_dwordx4 %9, %16, off offset:576 sc1\n\t"                   \
    "global_load_dwordx4 %10, %16, off offset:640 sc1\n\t"                  \
    "global_load_dwordx4 %11, %16, off offset:704 sc1\n\t"                  \
    "global_load_dwordx4 %12, %16, off offset:768 sc1\n\t"                  \
    "global_load_dwordx4 %13, %16, off offset:832 sc1\n\t"                  \
    "global_load_dwordx4 %14, %16, off offset:896 sc1\n\t"                  \
    "global_load_dwordx4 %15, %16, off offset:960 sc1\n\t"                  \
    "s_waitcnt vmcnt(0)"                                                    \
    : "=&v"(f[0]), "=&v"(f[1]), "=&v"(f[2]), "=&v"(f[3]),                   \
      "=&v"(f[4]), "=&v"(f[5]), "=&v"(f[6]), "=&v"(f[7]),                   \
      "=&v"(f[8]), "=&v"(f[9]), "=&v"(f[10]), "=&v"(f[11]),                 \
      "=&v"(f[12]), "=&v"(f[13]), "=&v"(f[14]), "=&v"(f[15])                \
    : "v"(p) : "memory")

// 32 loads from two rows in one batch (layer 1), single drain
#define LD16X2(f, g, p0, p1)                                                \
  asm volatile(                                                             \
    "global_load_dwordx4 %0, %32, off sc1\n\t"                              \
    "global_load_dwordx4 %16, %33, off sc1\n\t"                             \
    "global_load_dwordx4 %1, %32, off offset:64 sc1\n\t"                    \
    "global_load_dwordx4 %17, %33, off offset:64 sc1\n\t"                   \
    "global_load_dwordx4 %2, %32, off offset:128 sc1\n\t"                   \
    "global_load_dwordx4 %18, %33, off offset:128 sc1\n\t"                  \
    "global_load_dwordx4 %3, %32, off offset:192 sc1\n\t"                   \
    "global_load_dwordx4 %19, %33, off offset:192 sc1\n\t"                  \
    "global_load_dwordx4 %4, %32, off offset:256 sc1\n\t"                   \
    "global_load_dwordx4 %20, %33, off offset:256 sc1\n\t"                  \
    "global_load_dwordx4 %5, %32, off offset:320 sc1\n\t"                   \
    "global_load_dwordx4 %21, %33, off offset:320 sc1\n\t"                  \
    "global_load_dwordx4 %6, %32, off offset:384 sc1\n\t"                   \
    "global_load_dwordx4 %22, %33, off offset:384 sc1\n\t"                  \
    "global_load_dwordx4 %7, %32, off offset:448 sc1\n\t"                   \
    "global_load_dwordx4 %23, %33, off offset:448 sc1\n\t"                  \
    "global_load_dwordx4 %8, %32, off offset:512 sc1\n\t"                   \
    "global_load_dwordx4 %24, %33, off offset:512 sc1\n\t"                  \
    "global_load_dwordx4 %9, %32, off offset:576 sc1\n\t"                   \
    "global_load_dwordx4 %25, %33, off offset:576 sc1\n\t"                  \
    "global_load_dwordx4 %10, %32, off offset:640 sc1\n\t"                  \
    "global_load_dwordx4 %26, %33, off offset:640 sc1\n\t"                  \
    "global_load_dwordx4 %11, %32, off offset:704 sc1\n\t"                  \
    "global_load_dwordx4 %27, %33, off offset:704 sc1\n\t"                  \
    "global_load_dwordx4 %12, %32, off offset:768 sc1\n\t"                  \
    "global_load_dwordx4 %28, %33, off offset:768 sc1\n\t"                  \
    "global_load_dwordx4 %13, %32, off offset:832 sc1\n\t"                  \
    "global_load_dwordx4 %29, %33, off offset:832 sc1\n\t"                  \
    "global_load_dwordx4 %14, %32, off offset:896 sc1\n\t"                  \
    "global_load_dwordx4 %30, %33, off offset:896 sc1\n\t"                  \
    "global_load_dwordx4 %15, %32, off offset:960 sc1\n\t"                  \
    "global_load_dwordx4 %31, %33, off offset:960 sc1\n\t"                  \
    "s_waitcnt vmcnt(0)"                                                    \
    : "=&v"(f[0]), "=&v"(f[1]), "=&v"(f[2]), "=&v"(f[3]),                   \
      "=&v"(f[4]), "=&v"(f[5]), "=&v"(f[6]), "=&v"(f[7]),                   \
      "=&v"(f[8]), "=&v"(f[9]), "=&v"(f[10]), "=&v"(f[11]),                 \
      "=&v"(f[12]), "=&v"(f[13]), "=&v"(f[14]), "=&v"(f[15]),               \
      "=&v"(g[0]), "=&v"(g[1]), "=&v"(g[2]), "=&v"(g[3]),                   \
      "=&v"(g[4]), "=&v"(g[5]), "=&v"(g[6]), "=&v"(g[7]),                   \
      "=&v"(g[8]), "=&v"(g[9]), "=&v"(g[10]), "=&v"(g[11]),                 \
      "=&v"(g[12]), "=&v"(g[13]), "=&v"(g[14]), "=&v"(g[15])                \
    : "v"(p0), "v"(p1) : "memory")

#define WAITVM asm volatile("s_waitcnt vmcnt(0)" ::: "memory")

// ---- prep: fp32->bf16 conversions, bias sums, flag zeroing ----
__global__ void k_prep(const float* __restrict__ x,
                       const float* __restrict__ w0ih, const float* __restrict__ w0hh,
                       const float* __restrict__ b0i,  const float* __restrict__ b0h,
                       const float* __restrict__ w1ih, const float* __restrict__ w1hh,
                       const float* __restrict__ b1i,  const float* __restrict__ b1h,
                       u16* __restrict__ xb,
                       u16* __restrict__ w0ihb, u16* __restrict__ w0hhb,
                       u16* __restrict__ w1ihb, u16* __restrict__ w1hhb,
                       float* __restrict__ bias0, float* __restrict__ bias1,
                       int* __restrict__ flags)
{
    const int stride = gridDim.x * blockDim.x;
    const int tid = blockIdx.x * blockDim.x + threadIdx.x;
    for (int i = tid; i < M_TOT * H_D / 4; i += stride) {
        const float4 v = ((const float4*)x)[i];
        ushort4 o;
        o.x = f2bf(v.x); o.y = f2bf(v.y); o.z = f2bf(v.z); o.w = f2bf(v.w);
        ((ushort4*)xb)[i] = o;
    }
    for (int i = tid; i < H_D * H_D; i += stride) {
        w0ihb[i] = f2bf(w0ih[i]);
        w0hhb[i] = f2bf(w0hh[i]);
        w1ihb[i] = f2bf(w1ih[i]);
        w1hhb[i] = f2bf(w1hh[i]);
    }
    if (tid < H_D) {
        bias0[tid] = b0i[tid] + b0h[tid];
        bias1[tid] = b1i[tid] + b1h[tid];
    }
    if (tid < 192) flags[tid] = 0;
}

// ---- big parallel GEMM: out[M,512] = A @ W^T + bias (bf16 MFMA) ----
__global__ __launch_bounds__(256)
void k_gemm(const u16* __restrict__ A, const u16* __restrict__ W,
            const float* __restrict__ bias, float* __restrict__ out)
{
    __shared__ u16 As[128][40];
    __shared__ u16 Ws[128][40];
    const int m0 = blockIdx.x * 128;
    const int n0 = blockIdx.y * 128;
    const int tid = threadIdx.x;
    const int w = tid >> 6, l = tid & 63, q = l >> 4, lr = l & 15;
    const int mw = (w >> 1) * 64, nw = (w & 1) * 64;
    const int skg = (tid & 3) * 8;
    const int smr = tid >> 2;

    f32x4 acc[4][4];
    #pragma unroll
    for (int i = 0; i < 4; ++i)
        #pragma unroll
        for (int j = 0; j < 4; ++j)
            acc[i][j] = (f32x4){0.f, 0.f, 0.f, 0.f};

    for (int kk = 0; kk < H_D; kk += 32) {
        *(uint4*)&As[smr][skg]      = *(const uint4*)(A + (size_t)(m0 + smr) * H_D + kk + skg);
        *(uint4*)&As[smr + 64][skg] = *(const uint4*)(A + (size_t)(m0 + smr + 64) * H_D + kk + skg);
        *(uint4*)&Ws[smr][skg]      = *(const uint4*)(W + (size_t)(n0 + smr) * H_D + kk + skg);
        *(uint4*)&Ws[smr + 64][skg] = *(const uint4*)(W + (size_t)(n0 + smr + 64) * H_D + kk + skg);
        __syncthreads();
        short8 af[4], bf[4];
        #pragma unroll
        for (int rt = 0; rt < 4; ++rt) af[rt] = *(const short8*)&As[mw + rt*16 + lr][q*8];
        #pragma unroll
        for (int nt = 0; nt < 4; ++nt) bf[nt] = *(const short8*)&Ws[nw + nt*16 + lr][q*8];
        #pragma unroll
        for (int rt = 0; rt < 4; ++rt)
            #pragma unroll
            for (int nt = 0; nt < 4; ++nt)
                acc[rt][nt] = __builtin_amdgcn_mfma_f32_16x16x32_bf16(af[rt], bf[nt], acc[rt][nt], 0, 0, 0);
        __syncthreads();
    }
    #pragma unroll
    for (int nt = 0; nt < 4; ++nt) {
        const int col = n0 + nw + nt*16 + lr;
        const float bv = bias[col];
        #pragma unroll
        for (int rt = 0; rt < 4; ++rt) {
            #pragma unroll
            for (int r = 0; r < 4; ++r) {
                const int row = m0 + mw + rt*16 + q*4 + r;
                out[(size_t)row * H_D + col] = acc[rt][nt][r] + bv;
            }
        }
    }
}

// ---- fused 2-layer recurrence, pipelined across layers ----
// blocks 0..15: layer 0 (32-col slices).  blocks 16..47: layer 1 (16-col slices).
// hbuf slot s holds h[t = s-1]; slot 0 = h_init. flags [c][4w] = slots published.
__global__ __launch_bounds__(256, 1)
void k_rec_fused(const u16* __restrict__ Whh0, const u16* __restrict__ Wih1,
                 const u16* __restrict__ Whh1,
                 const float* __restrict__ h_init,
                 const float* __restrict__ pre0,
                 const float* __restrict__ bias1,
                 u16* __restrict__ h0buf, u16* __restrict__ h1buf,
                 float* __restrict__ out, float* __restrict__ hn,
                 int* __restrict__ flags0, int* __restrict__ flags1)
{
    const int tid = threadIdx.x;
    const int w = tid >> 6, l = tid & 63, q = l >> 4, lr = l & 15;
    const int r0 = w * 16;
    const int m = r0 + lr;

    if (blockIdx.x < 16) {
        // ================= layer 0: 32 columns =================
        const int c = blockIdx.x;
        const int nbase = c * 32;
        short8 breg[16][2];
        #pragma unroll
        for (int kt = 0; kt < 16; ++kt)
            #pragma unroll
            for (int nt = 0; nt < 2; ++nt)
                breg[kt][nt] = *(const short8*)(Whh0 + (size_t)(nbase + nt*16 + lr) * H_D + kt*32 + q*8);

        // stage 0: publish h_init slot 0 (our 16 rows x 32 cols)
        #pragma unroll
        for (int j = 0; j < 8; ++j) {
            int idx = l * 8 + j;
            int row = r0 + (idx >> 5);
            int col = nbase + (idx & 31);
            st_h(h0buf + (size_t)row * H_D + col, f2bf(h_init[row * H_D + col]));
        }
        WAITVM;
        if (l == 0) st_flag(flags0 + c*4 + w, 1);

        for (int t = 0; t < L_SEQ; ++t) {
            f32x4 acc0, acc1;
            const float* pt = pre0 + (size_t)t * (N_B * H_D);
            #pragma unroll
            for (int r = 0; r < 4; ++r) {
                acc0[r] = pt[(size_t)(r0 + q*4 + r) * H_D + nbase + lr];
                acc1[r] = pt[(size_t)(r0 + q*4 + r) * H_D + nbase + 16 + lr];
            }
            wait_flags16(flags0, w, t + 1);
            const u16* hs = h0buf + ((size_t)t * N_B + m) * H_D + q*8;
            i32x4 f[16];
            LD16(f, hs);
            #pragma unroll
            for (int kt = 0; kt < 16; ++kt) {
                short8 a = __builtin_bit_cast(short8, f[kt]);
                acc0 = __builtin_amdgcn_mfma_f32_16x16x32_bf16(a, breg[kt][0], acc0, 0, 0, 0);
                acc1 = __builtin_amdgcn_mfma_f32_16x16x32_bf16(a, breg[kt][1], acc1, 0, 0, 0);
            }
            float v0[4], v1[4];
            unsigned hv[8];
            #pragma unroll
            for (int r = 0; r < 4; ++r) {
                v0[r] = fast_tanh(acc0[r]);
                v1[r] = fast_tanh(acc1[r]);
                hv[2*r]   = f2bf(v0[r]);
                hv[2*r+1] = f2bf(v1[r]);
            }
            u16* hd = h0buf + (size_t)(t+1) * (N_B * H_D) + (size_t)(r0 + q*4) * H_D + nbase + lr;
            asm volatile(
                "global_store_short %8, %0, off sc1\n\t"
                "global_store_short %8, %1, off offset:32 sc1\n\t"
                "global_store_short %8, %2, off offset:1024 sc1\n\t"
                "global_store_short %8, %3, off offset:1056 sc1\n\t"
                "global_store_short %8, %4, off offset:2048 sc1\n\t"
                "global_store_short %8, %5, off offset:2080 sc1\n\t"
                "global_store_short %8, %6, off offset:3072 sc1\n\t"
                "global_store_short %8, %7, off offset:3104 sc1"
                :: "v"(hv[0]), "v"(hv[1]), "v"(hv[2]), "v"(hv[3]),
                   "v"(hv[4]), "v"(hv[5]), "v"(hv[6]), "v"(hv[7]), "v"(hd)
                : "memory");
            WAITVM;
            if (l == 0) st_flag(flags0 + c*4 + w, t + 2);
            if (t == L_SEQ - 1) {
                #pragma unroll
                for (int r = 0; r < 4; ++r) {
                    int row = r0 + q*4 + r;
                    hn[(size_t)row * H_D + nbase + lr]      = v0[r];
                    hn[(size_t)row * H_D + nbase + 16 + lr] = v1[r];
                }
            }
        }
    } else {
        // ================= layer 1: 16 columns =================
        const int c = blockIdx.x - 16;
        const int nbase = c * 16;
        short8 bregI[16], bregH[16];
        #pragma unroll
        for (int kt = 0; kt < 16; ++kt) {
            bregI[kt] = *(const short8*)(Wih1 + (size_t)(nbase + lr) * H_D + kt*32 + q*8);
            bregH[kt] = *(const short8*)(Whh1 + (size_t)(nbase + lr) * H_D + kt*32 + q*8);
        }
        const float bv = bias1[nbase + lr];

        const float* hi1 = h_init + N_B * H_D;
        #pragma unroll
        for (int j = 0; j < 4; ++j) {
            int idx = l * 4 + j;
            int row = r0 + (idx >> 4);
            int col = nbase + (idx & 15);
            st_h(h1buf + (size_t)row * H_D + col, f2bf(hi1[row * H_D + col]));
        }
        WAITVM;
        if (l == 0) st_flag(flags1 + c*4 + w, 1);

        for (int t = 0; t < L_SEQ; ++t) {
            wait_flags_l1(flags0, flags1, w, t);
            const u16* p0 = h0buf + ((size_t)(t+1) * N_B + m) * H_D + q*8;
            const u16* p1 = h1buf + ((size_t)t     * N_B + m) * H_D + q*8;
            i32x4 f[16], g[16];
            LD16X2(f, g, p0, p1);
            f32x4 accI = {bv, bv, bv, bv};
            f32x4 accH = {0.f, 0.f, 0.f, 0.f};
            #pragma unroll
            for (int kt = 0; kt < 16; ++kt) {
                accI = __builtin_amdgcn_mfma_f32_16x16x32_bf16(__builtin_bit_cast(short8, f[kt]), bregI[kt], accI, 0, 0, 0);
                accH = __builtin_amdgcn_mfma_f32_16x16x32_bf16(__builtin_bit_cast(short8, g[kt]), bregH[kt], accH, 0, 0, 0);
            }
            float v[4];
            unsigned hv[4];
            #pragma unroll
            for (int r = 0; r < 4; ++r) {
                v[r] = fast_tanh(accI[r] + accH[r]);
                hv[r] = f2bf(v[r]);
            }
            u16* hd = h1buf + (size_t)(t+1) * (N_B * H_D) + (size_t)(r0 + q*4) * H_D + nbase + lr;
            asm volatile(
                "global_store_short %4, %0, off sc1\n\t"
                "global_store_short %4, %1, off offset:1024 sc1\n\t"
                "global_store_short %4, %2, off offset:2048 sc1\n\t"
                "global_store_short %4, %3, off offset:3072 sc1"
                :: "v"(hv[0]), "v"(hv[1]), "v"(hv[2]), "v"(hv[3]), "v"(hd)
                : "memory");
            WAITVM;
            if (l == 0) st_flag(flags1 + c*4 + w, t + 2);
            float* od = out + (size_t)t * (N_B * H_D);
            #pragma unroll
            for (int r = 0; r < 4; ++r) {
                int row = r0 + q*4 + r;
                od[(size_t)row * H_D + nbase + lr] = v[r];
                if (t == L_SEQ - 1)
                    hn[(size_t)(N_B + row) * H_D + nbase + lr] = v[r];
            }
        }
    }
}

extern "C" void kernel_launch(void* const* d_in, const int* in_sizes, int n_in,
                              void* d_out, int out_size, void* d_ws, size_t ws_size,
                              hipStream_t stream)
{
    (void)in_sizes; (void)n_in; (void)out_size; (void)ws_size;
    const float* x    = (const float*)d_in[0];
    const float* h0   = (const float*)d_in[1];
    const float* w0ih = (const float*)d_in[2];
    const float* w0hh = (const float*)d_in[3];
    const float* b0i  = (const float*)d_in[4];
    const float* b0h  = (const float*)d_in[5];
    const float* w1ih = (const float*)d_in[6];
    const float* w1hh = (const float*)d_in[7];
    const float* b1i  = (const float*)d_in[8];
    const float* b1h  = (const float*)d_in[9];
    float* out = (float*)d_out;
    float* hn  = out + (size_t)M_TOT * H_D;

    char* ws = (char*)d_ws;
    size_t off = 0;
    u16* w0ihb = (u16*)(ws + off);   off += (size_t)H_D * H_D * 2;
    u16* w0hhb = (u16*)(ws + off);   off += (size_t)H_D * H_D * 2;
    u16* w1ihb = (u16*)(ws + off);   off += (size_t)H_D * H_D * 2;
    u16* w1hhb = (u16*)(ws + off);   off += (size_t)H_D * H_D * 2;
    float* bias0 = (float*)(ws + off); off += H_D * 4;
    float* bias1 = (float*)(ws + off); off += H_D * 4;
    int* flags   = (int*)(ws + off);   off += 256 * 4;
    int* flags0  = flags;
    int* flags1  = flags + 64;
    u16* h0buf   = (u16*)(ws + off);   off += (size_t)(L_SEQ + 1) * N_B * H_D * 2;
    float* pre0  = (float*)(ws + off); off += (size_t)M_TOT * H_D * 4;
    u16* h1buf   = (u16*)(ws + off);   off += (size_t)(L_SEQ + 1) * N_B * H_D * 2;
    u16* xb      = h1buf;   // xb dead after k_gemm; aliases h1buf

    k_prep<<<2048, 256, 0, stream>>>(x, w0ih, w0hh, b0i, b0h, w1ih, w1hh, b1i, b1h,
                                     xb, w0ihb, w0hhb, w1ihb, w1hhb,
                                     bias0, bias1, flags);
    k_gemm<<<dim3(M_TOT/128, H_D/128), 256, 0, stream>>>(xb, w0ihb, bias0, pre0);
    k_rec_fused<<<48, 256, 0, stream>>>(w0hhb, w1ihb, w1hhb, h0, pre0, bias1,
                                        h0buf, h1buf, out, hn, flags0, flags1);
}